// Round 11
// baseline (41.149 us; speedup 1.0000x reference)
//
#include <hip/hip_runtime.h>

#define NB 256
#define NS 2048
#define NP 64
#define ND 80
#define STILE 128
#define NTILE 16            // NS/STILE
#define NTHREADS 1024
#define LOG2E 1.4426950408889634f
#define BUFU 12672          // u16 per enc buffer
#define BUFB 25344          // bytes per enc buffer

typedef __attribute__((ext_vector_type(4))) float f32x4;
typedef __attribute__((ext_vector_type(2))) __fp16 fp16x2;
typedef __attribute__((ext_vector_type(8))) _Float16 f16x8;
typedef __attribute__((ext_vector_type(4))) unsigned short u16x4;
typedef unsigned short u16;

// ---------------- LDS layout (bytes) ----------------
// buf[3]: u16[8][6][264] each @ k*25344, k=0..2 (76032 total) — f16 enc in 16x16 [s][d]
//         row-major regions; region(q,n) = (q*6+n)*264 u16; n=5 = K-pad (zeroed once).
//         TRIPLE buffered: iter t QK-reads buf[t%3], PV-reads buf[(t-1)%3],
//         stage-writes buf[(t+1)%3] — disjoint, 1 barrier/iter, no race.
// mbias f32[2048] @ 76032 (8192)   0.0 / -3e38 per s
// mst f32[4][64] @ 84224 ; lst f32[4][64] @ 85248 ; modep @ 86272
// prologue overlay: W f32[80][84]@0 ; dec f32[64][84]@26880 ; qtmp f32[64][100]@0
// epilogue overlay: cacc f32[64][84]@0 (after PV(15) completes + barrier)
#define SMEM_BYTES 86288

__device__ __forceinline__ float E2(float x) { return __builtin_amdgcn_exp2f(x); }
// f32x2 -> f16x2 (RTZ, single v_cvt_pkrtz_f16_f32)
__device__ __forceinline__ unsigned pkh(float lo, float hi) {
  union { fp16x2 h; unsigned u; } cv;
  cv.h = __builtin_amdgcn_cvt_pkrtz(lo, hi);
  return cv.u;
}

// 16x16 K=32 f16 MFMA. C/D: col=lane&15, row=4*(lane>>4)+r (dtype-independent).
// A and B share the (lane-group g, reg-slot j) -> k=8g+j map (verified R2-R10).
__device__ __forceinline__ f32x4 mfma16f(f16x8 a, f16x8 b, f32x4 c) {
  return __builtin_amdgcn_mfma_f32_16x16x32_f16(a, b, c, 0, 0, 0);
}

__global__ __launch_bounds__(NTHREADS, 4)
void DecoderAttention_62989990363717_kernel(const float* __restrict__ enc,
                                            const float* __restrict__ dec,
                                            const int* __restrict__ maskp,
                                            const float* __restrict__ W,
                                            float* __restrict__ out)
{
  __shared__ __align__(16) char smem[SMEM_BYTES];

  u16* ehP    = (u16*)smem;               // [3][12672]
  float* mbias = (float*)(smem + 76032);  // [2048]
  float* mst  = (float*)(smem + 84224);   // [4][64]
  float* lst  = (float*)(smem + 85248);   // [4][64]
  int* modep  = (int*)(smem + 86272);

  const int tid  = (int)threadIdx.x;
  const int lane = tid & 63;
  const int wv   = tid >> 6;    // 0..15
  const int pp   = wv & 3;      // p-block: rows [16*pp, 16*pp+16)
  const int sq   = wv >> 2;     // 32-row s-slice within tile: quarters {2sq, 2sq+1}
  const int l15  = lane & 15;
  const int g    = lane >> 4;
  const int b    = (int)blockIdx.x;

  const float* encB = enc + (size_t)b * NS * ND;
  const float* decB = dec + (size_t)b * NP * ND;

  // ---------- prologue: W, dec(scaled) -> LDS; mask->bias; Q ----------
  {
    float* Wl = (float*)smem;            // [80][84]
    float* dl = (float*)(smem + 26880);  // [64][84]
    for (int i = tid; i < 80 * 80; i += NTHREADS) Wl[(i / 80) * 84 + (i % 80)] = W[i];
    for (int i = tid; i < 64 * 80; i += NTHREADS)
      dl[(i / 80) * 84 + (i % 80)] = decB[i] * LOG2E;   // exp2-domain scores
    if (tid == 0) {
      const unsigned* mw = (const unsigned*)maskp;
      int ok = 1;
      for (int i = 0; i < 16; ++i) ok &= (mw[i] <= 1u);
      *modep = ok;   // 1 => int32 mask, 0 => int8 mask
    }
    __syncthreads();
    const int m32 = *modep;
    if (m32) {
      int v0 = maskp[(size_t)b * NS + tid];
      int v1 = maskp[(size_t)b * NS + tid + 1024];
      mbias[tid]        = v0 ? -3.0e38f : 0.0f;
      mbias[tid + 1024] = v1 ? -3.0e38f : 0.0f;
    } else if (tid < 512) {
      unsigned w = ((const unsigned*)maskp)[(size_t)b * (NS / 4) + tid];
      f32x4 bb;
      bb[0] = (w & 255u)         ? -3.0e38f : 0.0f;
      bb[1] = ((w >> 8) & 255u)  ? -3.0e38f : 0.0f;
      bb[2] = ((w >> 16) & 255u) ? -3.0e38f : 0.0f;
      bb[3] = (w >> 24)          ? -3.0e38f : 0.0f;
      *(f32x4*)&mbias[4 * tid] = bb;
    }
    // Q = dec @ W^T in fp32 (all 1024 threads: p = tid&63, e-range = 5*qw)
    float qa[5];
    const int qp = tid & 63, qw = tid >> 6;   // qw 0..15
#pragma unroll
    for (int j = 0; j < 5; ++j) qa[j] = 0.f;
    for (int kg = 0; kg < 20; ++kg) {
      f32x4 dv = *(const f32x4*)&dl[qp * 84 + kg * 4];
#pragma unroll
      for (int j = 0; j < 5; ++j) {
        f32x4 wv4 = *(const f32x4*)&Wl[(qw * 5 + j) * 84 + kg * 4];
        qa[j] = fmaf(dv.x, wv4.x, qa[j]);
        qa[j] = fmaf(dv.y, wv4.y, qa[j]);
        qa[j] = fmaf(dv.z, wv4.z, qa[j]);
        qa[j] = fmaf(dv.w, wv4.w, qa[j]);
      }
    }
    __syncthreads();            // Wl/dl reads done
    float* qtmp = (float*)smem; // [64][100], zeros at d=80..95
#pragma unroll
    for (int j = 0; j < 5; ++j) qtmp[qp * 100 + qw * 5 + j] = qa[j];
    if (qw == 15) {
#pragma unroll
      for (int z = 0; z < 16; ++z) qtmp[qp * 100 + 80 + z] = 0.f;
    }
    __syncthreads();
  }

  // ---------- Q fragments (persistent, f16 hi/lo split, RNE) ----------
  f16x8 qb[3], qlb[3];
  {
    const float* qtmp = (const float*)smem;
    const int prow = 16 * pp + l15;
#pragma unroll
    for (int kk = 0; kk < 3; ++kk) {
      const int d0 = kk * 32 + g * 8;
      f32x4 f0 = *(const f32x4*)&qtmp[prow * 100 + d0];
      f32x4 f1 = *(const f32x4*)&qtmp[prow * 100 + d0 + 4];
      float fq[8] = {f0.x, f0.y, f0.z, f0.w, f1.x, f1.y, f1.z, f1.w};
      union { _Float16 h[8]; f16x8 v; } H, L;
#pragma unroll
      for (int j = 0; j < 8; ++j) {
        _Float16 hh = (_Float16)fq[j];          // RNE
        H.h[j] = hh;
        L.h[j] = (_Float16)(fq[j] - (float)hh); // residual ~2^-11
      }
      qb[kk] = H.v; qlb[kk] = L.v;
    }
  }
  __syncthreads();   // qtmp dead; staging may overwrite

  // ---------- zero K-pad regions (n=5) once: 3 buffers x 8 quarters ----------
  if (tid < 384) {
    const int buf = tid >> 7, q = (tid >> 4) & 7, row = tid & 15;
    u16* p = ehP + buf * BUFU + (q * 6 + 5) * 264 + row * 16;
    *(uint4*)p = make_uint4(0u, 0u, 0u, 0u);
    *(uint4*)(p + 8) = make_uint4(0u, 0u, 0u, 0u);
  }

  // loader roles: tid<640 stage enc (5 threads/row, 16 f32 each, all-b128 writes)
  const bool ldr = (tid < 640);
  const int srow = tid / 5;                 // 0..127
  const int c    = tid - srow * 5;          // 0..4 (d-block of 16)
  u16* ePW = ehP + ((srow >> 4) * 6 + c) * 264 + (srow & 15) * 16;
  const float* gsrc = encB + srow * ND + 16 * c;

#define STAGE_WRITE(ofsU16)                                                      \
  do {                                                                           \
    if (ldr) {                                                                   \
      unsigned hh[8];                                                            \
      hh[0] = pkh(r0.x, r0.y); hh[1] = pkh(r0.z, r0.w);                          \
      hh[2] = pkh(r1.x, r1.y); hh[3] = pkh(r1.z, r1.w);                          \
      hh[4] = pkh(r2.x, r2.y); hh[5] = pkh(r2.z, r2.w);                          \
      hh[6] = pkh(r3.x, r3.y); hh[7] = pkh(r3.z, r3.w);                          \
      u16* a_ = ePW + (ofsU16);                                                  \
      *(uint4*)a_       = make_uint4(hh[0], hh[1], hh[2], hh[3]);                \
      *(uint4*)(a_ + 8) = make_uint4(hh[4], hh[5], hh[6], hh[7]);                \
    }                                                                            \
  } while (0)

  // QK A-frag base (u16 idx): region(2sq+blk, (g>>1)+2kk) + 16*l15 + 8*(g&1)
  const int qkOff = (2 * sq) * 1584 + (g >> 1) * 264 + 16 * l15 + 8 * (g & 1);
  // PV tr-read base (bytes): region(2sq, n) + 8*lane; blk1 = +3168B, n-step = 528B
  const unsigned trBase = (unsigned)(uintptr_t)ehP + (unsigned)(sq * 6336 + 8 * lane);

#define QK_COMPUTE(ofsU16, A0, A1)                                               \
  do {                                                                           \
    const u16* baseH0 = ehP + (ofsU16) + qkOff;                                  \
    const u16* baseH1 = baseH0 + 1584;                                           \
    f16x8 e0[3], e1[3];                                                          \
    _Pragma("unroll")                                                            \
    for (int kk = 0; kk < 3; ++kk) {                                             \
      e0[kk] = *(const f16x8*)(const void*)(baseH0 + kk * 528);                  \
      e1[kk] = *(const f16x8*)(const void*)(baseH1 + kk * 528);                  \
    }                                                                            \
    _Pragma("unroll")                                                            \
    for (int kk = 0; kk < 3; ++kk) {                                             \
      A0 = mfma16f(e0[kk], qb[kk], A0);                                          \
      A1 = mfma16f(e1[kk], qb[kk], A1);                                          \
      A0 = mfma16f(e0[kk], qlb[kk], A0);                                         \
      A1 = mfma16f(e1[kk], qlb[kk], A1);                                         \
    }                                                                            \
  } while (0)

  // ---------- main state ----------
  f32x4 ctx[5];
#pragma unroll
  for (int n = 0; n < 5; ++n) ctx[n] = (f32x4){0.f, 0.f, 0.f, 0.f};
  float mr = -3.0e38f, lr = 0.f;   // lr: per-lane partial (reduced in epilogue)
  f32x4 sp0, sp1;                  // carried scores of tile t-1

  // ---------- prologue stages: tile 0 ready; QK(0); tile 1 ready ----------
  {
    f32x4 r0, r1, r2, r3;
    if (ldr) {
      r0 = *(const f32x4*)gsrc;       r1 = *(const f32x4*)(gsrc + 4);
      r2 = *(const f32x4*)(gsrc + 8); r3 = *(const f32x4*)(gsrc + 12);
    }
    STAGE_WRITE(0);
    __syncthreads();
  }
  {
    f32x4 r0, r1, r2, r3;
    if (ldr) {
      const float* src = gsrc + (size_t)STILE * ND;
      r0 = *(const f32x4*)src;       r1 = *(const f32x4*)(src + 4);
      r2 = *(const f32x4*)(src + 8); r3 = *(const f32x4*)(src + 12);
    }
    f32x4 a0 = (f32x4){0.f,0.f,0.f,0.f}, a1 = (f32x4){0.f,0.f,0.f,0.f};
    QK_COMPUTE(0, a0, a1);          // QK(0) from buf0
    STAGE_WRITE(BUFU);              // tile 1 -> buf1
    __syncthreads();
    sp0 = a0; sp1 = a1;
  }

  // ---------- staggered main loop: t = 1..15 ----------
  int oA = BUFU, oP = 0, oW = 2 * BUFU;   // QK buf, PV buf (t-1), write buf (t+1)
  for (int tt = 1; tt < NTILE; ++tt) {
    const bool hn = (tt + 1 < NTILE);
    f32x4 r0, r1, r2, r3;
    if (hn && ldr) {
      const float* src = gsrc + (size_t)(tt + 1) * STILE * ND;
      r0 = *(const f32x4*)src;       r1 = *(const f32x4*)(src + 4);
      r2 = *(const f32x4*)(src + 8); r3 = *(const f32x4*)(src + 12);
    }

    // ---- QK(t): MFMA only; results not needed until next iteration ----
    f32x4 a0 = (f32x4){0.f,0.f,0.f,0.f}, a1 = (f32x4){0.f,0.f,0.f,0.f};
    QK_COMPUTE(oA, a0, a1);

    // ---- SM(t-1) + PV(t-1): depends only on sp (resolved) + buf oP ----
    {
      const int mb0 = (tt - 1) * 128 + 32 * sq + 4 * g;
      f32x4 bias0 = *(const f32x4*)&mbias[mb0];
      f32x4 bias1 = *(const f32x4*)&mbias[mb0 + 16];
      float sv0[4], sv1[4];
#pragma unroll
      for (int rr = 0; rr < 4; ++rr) {
        sv0[rr] = sp0[rr] + bias0[rr];
        sv1[rr] = sp1[rr] + bias1[rr];
      }
      float tm = fmaxf(fmaxf(fmaxf(sv0[0], sv0[1]), fmaxf(sv0[2], sv0[3])),
                       fmaxf(fmaxf(sv1[0], sv1[1]), fmaxf(sv1[2], sv1[3])));
      tm = fmaxf(tm, __shfl_xor(tm, 16));
      tm = fmaxf(tm, __shfl_xor(tm, 32));
      const bool need = !__all(tm <= mr + 11.541560f);   // 8 * log2(e)
      if (need) {
        float mn = fmaxf(mr, tm);
        float esc = E2(mr - mn);
        lr *= esc; mr = mn;
        float fr[4];
#pragma unroll
        for (int rr = 0; rr < 4; ++rr) fr[rr] = __shfl(esc, 4 * g + rr);
#pragma unroll
        for (int n = 0; n < 5; ++n) {
#pragma unroll
          for (int rr = 0; rr < 4; ++rr) ctx[n][rr] *= fr[rr];
        }
      }
      float p0[4], p1[4];
#pragma unroll
      for (int rr = 0; rr < 4; ++rr) {
        p0[rr] = E2(sv0[rr] - mr);
        p1[rr] = E2(sv1[rr] - mr);
      }
      lr += ((p0[0] + p0[1]) + (p0[2] + p0[3])) + ((p1[0] + p1[1]) + (p1[2] + p1[3]));

      union { unsigned uu[4]; f16x8 v; } PA;
      PA.uu[0] = pkh(p0[0], p0[1]); PA.uu[1] = pkh(p0[2], p0[3]);
      PA.uu[2] = pkh(p1[0], p1[1]); PA.uu[3] = pkh(p1[2], p1[3]);
      const unsigned tra = trBase + (unsigned)(oP * 2);
      {
        u16x4 ta0, tb0, ta1, tb1, ta2, tb2;
        asm volatile("ds_read_b64_tr_b16 %0, %1"             : "=v"(ta0) : "v"(tra));
        asm volatile("ds_read_b64_tr_b16 %0, %1 offset:3168" : "=v"(tb0) : "v"(tra));
        asm volatile("ds_read_b64_tr_b16 %0, %1 offset:528"  : "=v"(ta1) : "v"(tra));
        asm volatile("ds_read_b64_tr_b16 %0, %1 offset:3696" : "=v"(tb1) : "v"(tra));
        asm volatile("ds_read_b64_tr_b16 %0, %1 offset:1056" : "=v"(ta2) : "v"(tra));
        asm volatile("ds_read_b64_tr_b16 %0, %1 offset:4224" : "=v"(tb2) : "v"(tra));
        asm volatile("s_waitcnt lgkmcnt(0)" ::: "memory");
        __builtin_amdgcn_sched_barrier(0);
        union { u16 s[8]; f16x8 v; } B0, B1, B2;
#pragma unroll
        for (int j = 0; j < 4; ++j) {
          B0.s[j] = ta0[j]; B0.s[4 + j] = tb0[j];
          B1.s[j] = ta1[j]; B1.s[4 + j] = tb1[j];
          B2.s[j] = ta2[j]; B2.s[4 + j] = tb2[j];
        }
        ctx[0] = mfma16f(PA.v, B0.v, ctx[0]);
        ctx[1] = mfma16f(PA.v, B1.v, ctx[1]);
        ctx[2] = mfma16f(PA.v, B2.v, ctx[2]);
      }
      {
        u16x4 ta3, tb3, ta4, tb4;
        asm volatile("ds_read_b64_tr_b16 %0, %1 offset:1584" : "=v"(ta3) : "v"(tra));
        asm volatile("ds_read_b64_tr_b16 %0, %1 offset:4752" : "=v"(tb3) : "v"(tra));
        asm volatile("ds_read_b64_tr_b16 %0, %1 offset:2112" : "=v"(ta4) : "v"(tra));
        asm volatile("ds_read_b64_tr_b16 %0, %1 offset:5280" : "=v"(tb4) : "v"(tra));
        asm volatile("s_waitcnt lgkmcnt(0)" ::: "memory");
        __builtin_amdgcn_sched_barrier(0);
        union { u16 s[8]; f16x8 v; } B3, B4;
#pragma unroll
        for (int j = 0; j < 4; ++j) {
          B3.s[j] = ta3[j]; B3.s[4 + j] = tb3[j];
          B4.s[j] = ta4[j]; B4.s[4 + j] = tb4[j];
        }
        ctx[3] = mfma16f(PA.v, B3.v, ctx[3]);
        ctx[4] = mfma16f(PA.v, B4.v, ctx[4]);
      }
    }

    if (hn) { STAGE_WRITE(oW); }
    __syncthreads();
    sp0 = a0; sp1 = a1;
    const int t2 = oP; oP = oA; oA = oW; oW = t2;   // rotate buffers
  }

  // ---------- tail: SM(15) + PV(15) (buf oP = buf0) ----------
  {
    const int mb0 = (NTILE - 1) * 128 + 32 * sq + 4 * g;
    f32x4 bias0 = *(const f32x4*)&mbias[mb0];
    f32x4 bias1 = *(const f32x4*)&mbias[mb0 + 16];
    float sv0[4], sv1[4];
#pragma unroll
    for (int rr = 0; rr < 4; ++rr) {
      sv0[rr] = sp0[rr] + bias0[rr];
      sv1[rr] = sp1[rr] + bias1[rr];
    }
    float tm = fmaxf(fmaxf(fmaxf(sv0[0], sv0[1]), fmaxf(sv0[2], sv0[3])),
                     fmaxf(fmaxf(sv1[0], sv1[1]), fmaxf(sv1[2], sv1[3])));
    tm = fmaxf(tm, __shfl_xor(tm, 16));
    tm = fmaxf(tm, __shfl_xor(tm, 32));
    const bool need = !__all(tm <= mr + 11.541560f);
    if (need) {
      float mn = fmaxf(mr, tm);
      float esc = E2(mr - mn);
      lr *= esc; mr = mn;
      float fr[4];
#pragma unroll
      for (int rr = 0; rr < 4; ++rr) fr[rr] = __shfl(esc, 4 * g + rr);
#pragma unroll
      for (int n = 0; n < 5; ++n) {
#pragma unroll
        for (int rr = 0; rr < 4; ++rr) ctx[n][rr] *= fr[rr];
      }
    }
    float p0[4], p1[4];
#pragma unroll
    for (int rr = 0; rr < 4; ++rr) {
      p0[rr] = E2(sv0[rr] - mr);
      p1[rr] = E2(sv1[rr] - mr);
    }
    lr += ((p0[0] + p0[1]) + (p0[2] + p0[3])) + ((p1[0] + p1[1]) + (p1[2] + p1[3]));

    union { unsigned uu[4]; f16x8 v; } PA;
    PA.uu[0] = pkh(p0[0], p0[1]); PA.uu[1] = pkh(p0[2], p0[3]);
    PA.uu[2] = pkh(p1[0], p1[1]); PA.uu[3] = pkh(p1[2], p1[3]);
    const unsigned tra = trBase + (unsigned)(oP * 2);
    {
      u16x4 ta0, tb0, ta1, tb1, ta2, tb2;
      asm volatile("ds_read_b64_tr_b16 %0, %1"             : "=v"(ta0) : "v"(tra));
      asm volatile("ds_read_b64_tr_b16 %0, %1 offset:3168" : "=v"(tb0) : "v"(tra));
      asm volatile("ds_read_b64_tr_b16 %0, %1 offset:528"  : "=v"(ta1) : "v"(tra));
      asm volatile("ds_read_b64_tr_b16 %0, %1 offset:3696" : "=v"(tb1) : "v"(tra));
      asm volatile("ds_read_b64_tr_b16 %0, %1 offset:1056" : "=v"(ta2) : "v"(tra));
      asm volatile("ds_read_b64_tr_b16 %0, %1 offset:4224" : "=v"(tb2) : "v"(tra));
      asm volatile("s_waitcnt lgkmcnt(0)" ::: "memory");
      __builtin_amdgcn_sched_barrier(0);
      union { u16 s[8]; f16x8 v; } B0, B1, B2;
#pragma unroll
      for (int j = 0; j < 4; ++j) {
        B0.s[j] = ta0[j]; B0.s[4 + j] = tb0[j];
        B1.s[j] = ta1[j]; B1.s[4 + j] = tb1[j];
        B2.s[j] = ta2[j]; B2.s[4 + j] = tb2[j];
      }
      ctx[0] = mfma16f(PA.v, B0.v, ctx[0]);
      ctx[1] = mfma16f(PA.v, B1.v, ctx[1]);
      ctx[2] = mfma16f(PA.v, B2.v, ctx[2]);
    }
    {
      u16x4 ta3, tb3, ta4, tb4;
      asm volatile("ds_read_b64_tr_b16 %0, %1 offset:1584" : "=v"(ta3) : "v"(tra));
      asm volatile("ds_read_b64_tr_b16 %0, %1 offset:4752" : "=v"(tb3) : "v"(tra));
      asm volatile("ds_read_b64_tr_b16 %0, %1 offset:2112" : "=v"(ta4) : "v"(tra));
      asm volatile("ds_read_b64_tr_b16 %0, %1 offset:5280" : "=v"(tb4) : "v"(tra));
      asm volatile("s_waitcnt lgkmcnt(0)" ::: "memory");
      __builtin_amdgcn_sched_barrier(0);
      union { u16 s[8]; f16x8 v; } B3, B4;
#pragma unroll
      for (int j = 0; j < 4; ++j) {
        B3.s[j] = ta3[j]; B3.s[4 + j] = tb3[j];
        B4.s[j] = ta4[j]; B4.s[4 + j] = tb4[j];
      }
      ctx[3] = mfma16f(PA.v, B3.v, ctx[3]);
      ctx[4] = mfma16f(PA.v, B4.v, ctx[4]);
    }
  }

  // ---------- epilogue: reduce lr, merge 4 s-slices, normalize, write ----------
  lr += __shfl_xor(lr, 16);
  lr += __shfl_xor(lr, 32);
  if (g == 0) {
    mst[sq * 64 + 16 * pp + l15] = mr;
    lst[sq * 64 + 16 * pp + l15] = lr;
  }
  __syncthreads();
  float F;
  {
    const int pi = 16 * pp + l15;
    float M = fmaxf(fmaxf(mst[pi], mst[64 + pi]), fmaxf(mst[128 + pi], mst[192 + pi]));
    F = E2(mr - M);
  }
  float gg[4];
#pragma unroll
  for (int rr = 0; rr < 4; ++rr) gg[rr] = __shfl(F, 4 * g + rr);
  float* cacc = (float*)smem;  // [64][84] (overwrites buf0 — PV(15) reads done, barrier above)
  for (int qq = 0; qq < 4; ++qq) {
    if (sq == qq) {
#pragma unroll
      for (int n = 0; n < 5; ++n) {
#pragma unroll
        for (int rr = 0; rr < 4; ++rr) {
          const int row = 16 * pp + 4 * g + rr;
          const int col = 16 * n + l15;
          float v = ctx[n][rr] * gg[rr];
          if (qq == 0) cacc[row * 84 + col] = v;
          else         cacc[row * 84 + col] += v;
        }
      }
    }
    __syncthreads();
  }
  {
    const int op = tid >> 4, oc = tid & 15;
    float Mv = fmaxf(fmaxf(mst[op], mst[64 + op]), fmaxf(mst[128 + op], mst[192 + op]));
    float Lv = lst[op] * E2(mst[op] - Mv) + lst[64 + op] * E2(mst[64 + op] - Mv)
             + lst[128 + op] * E2(mst[128 + op] - Mv) + lst[192 + op] * E2(mst[192 + op] - Mv);
    float inv = 1.0f / Lv;
    float* orow = out + ((size_t)b * NP + op) * ND + oc * 5;
    const float* crow = cacc + op * 84 + oc * 5;
#pragma unroll
    for (int i = 0; i < 5; ++i) orow[i] = crow[i] * inv;
  }
}

extern "C" void kernel_launch(void* const* d_in, const int* in_sizes, int n_in,
                              void* d_out, int out_size, void* d_ws, size_t ws_size,
                              hipStream_t stream) {
  (void)in_sizes; (void)n_in; (void)out_size; (void)d_ws; (void)ws_size;
  const float* enc  = (const float*)d_in[0];
  const float* dec  = (const float*)d_in[1];
  const int*   mask = (const int*)d_in[2];
  const float* W    = (const float*)d_in[3];
  float* out = (float*)d_out;
  DecoderAttention_62989990363717_kernel<<<dim3(NB), dim3(NTHREADS), 0, stream>>>(
      enc, dec, mask, W, out);
}